// Round 2
// baseline (549.430 us; speedup 1.0000x reference)
//
#include <hip/hip_runtime.h>
#include <hip/hip_bf16.h>
#include <stdint.h>

#define IN_F   4096
#define OUT_F  4096
#define M_TOT  8192   // 4 * 2048

typedef __bf16 bf16x8 __attribute__((ext_vector_type(8)));
typedef float  floatx4 __attribute__((ext_vector_type(4)));

__device__ __forceinline__ unsigned f2bf_bits(float f) {
    union { float f; uint32_t u; } v; v.f = f;
    uint32_t r = v.u + 0x7FFF + ((v.u >> 16) & 1);   // RNE
    return r >> 16;
}

__device__ __forceinline__ void gl_lds16(const void* g, void* l) {
    __builtin_amdgcn_global_load_lds(
        (const __attribute__((address_space(1))) void*)g,
        (__attribute__((address_space(3))) void*)l, 16, 0, 0);
}

#define X_BLOCKS 16384   // 33,554,432 floats / 8 per thread / 256
#define W_BLOCKS 8192    // 8,388,608 packed / 4 per thread / 256

// Fused prep: blocks [0,X_BLOCKS) convert x fp32->bf16 (8 elems/thread);
// blocks [X_BLOCKS, X_BLOCKS+W_BLOCKS) dequant packed int4 -> bf16 W.
__global__ void prep_kernel(const float* __restrict__ x, ushort* __restrict__ xb,
                            const int* __restrict__ packed,
                            const float* __restrict__ scales,
                            const float* __restrict__ offsets,
                            ushort* __restrict__ wb) {
    if (blockIdx.x < X_BLOCKS) {
        int i = blockIdx.x * 256 + threadIdx.x;      // 8 floats per thread
        float4 v0 = reinterpret_cast<const float4*>(x)[2 * i];
        float4 v1 = reinterpret_cast<const float4*>(x)[2 * i + 1];
        uint4 o;
        o.x = f2bf_bits(v0.x) | (f2bf_bits(v0.y) << 16);
        o.y = f2bf_bits(v0.z) | (f2bf_bits(v0.w) << 16);
        o.z = f2bf_bits(v1.x) | (f2bf_bits(v1.y) << 16);
        o.w = f2bf_bits(v1.z) | (f2bf_bits(v1.w) << 16);
        reinterpret_cast<uint4*>(xb)[i] = o;
    } else {
        int i = (blockIdx.x - X_BLOCKS) * 256 + threadIdx.x;  // 4 packed ints
        int4 p = reinterpret_cast<const int4*>(packed)[i];
        int g = i >> 4;                                       // (8*i)/128
        float s = scales[g], off = offsets[g];
        uint4 ov;
        ov.x = f2bf_bits((float)(p.x & 0xF) * s + off) |
               (f2bf_bits((float)((p.x >> 4) & 0xF) * s + off) << 16);
        ov.y = f2bf_bits((float)(p.y & 0xF) * s + off) |
               (f2bf_bits((float)((p.y >> 4) & 0xF) * s + off) << 16);
        ov.z = f2bf_bits((float)(p.z & 0xF) * s + off) |
               (f2bf_bits((float)((p.z >> 4) & 0xF) * s + off) << 16);
        ov.w = f2bf_bits((float)(p.w & 0xF) * s + off) |
               (f2bf_bits((float)((p.w >> 4) & 0xF) * s + off) << 16);
        reinterpret_cast<uint4*>(wb)[i] = ov;
    }
}

// ---- GEMM: C[M_TOT][OUT_F] = A[M_TOT][IN_F] * B[OUT_F][IN_F]^T + bias ----
// 128x128 tile, BK=32, 256 threads (2x2 waves, each 64x64 via 4x4 MFMA 16x16x32).
// LDS layout XOR-swizzled: tile row r, logical 16B k-chunk l stored at
// physical chunk p = l ^ ((r>>1)&3). Staging permutes GLOBAL source addrs
// (global_load_lds dst must stay base+lane*16); readers apply same swizzle.
__global__ void gemm_kernel(const ushort* __restrict__ A,   // bf16 [M_TOT][IN_F]
                            const ushort* __restrict__ B,   // bf16 [OUT_F][IN_F]
                            const float* __restrict__ bias,
                            float* __restrict__ C) {
    __shared__ __align__(16) ushort As[128 * 32];
    __shared__ __align__(16) ushort Bs[128 * 32];

    const int tid  = threadIdx.x;
    const int wave = tid >> 6;
    const int lane = tid & 63;
    const int quad = lane >> 4;
    const int l16  = lane & 15;
    const int wm   = wave >> 1;
    const int wn   = wave & 1;

    const int bm = blockIdx.y;
    const int bn = blockIdx.x;

    // staging chunk c -> LDS bytes [c*16, c*16+16); r = c>>2, physical p = c&3,
    // logical k-chunk l = p ^ ((r>>1)&3); global col = l*8 ushorts
    const int c0 = tid, c1 = 256 + tid;
    const int r0 = c0 >> 2, l0 = (c0 & 3) ^ ((r0 >> 1) & 3);
    const int r1 = c1 >> 2, l1 = (c1 & 3) ^ ((r1 >> 1) & 3);

    const ushort* gA0 = A + (size_t)(bm * 128 + r0) * IN_F + l0 * 8;
    const ushort* gA1 = A + (size_t)(bm * 128 + r1) * IN_F + l1 * 8;
    const ushort* gB0 = B + (size_t)(bn * 128 + r0) * IN_F + l0 * 8;
    const ushort* gB1 = B + (size_t)(bn * 128 + r1) * IN_F + l1 * 8;

    // wave-uniform LDS destinations: base = issue*4096 + wave*1024 bytes
    char* lA0 = (char*)As + wave * 1024;
    char* lA1 = (char*)As + 4096 + wave * 1024;
    char* lB0 = (char*)Bs + wave * 1024;
    char* lB1 = (char*)Bs + 4096 + wave * 1024;

    floatx4 acc[4][4] = {};

    const int arow = wm * 64 + l16;   // + mi*16
    const int brow = wn * 64 + l16;   // + ni*16
    // reader swizzle: row = (wm*64 + l16 + mi*16) -> ((row>>1)&3) == ((l16>>1)&3)
    const int koff = (quad ^ ((l16 >> 1) & 3)) * 8;

    for (int k0 = 0; k0 < IN_F; k0 += 32) {
        gl_lds16(gA0, lA0);
        gl_lds16(gA1, lA1);
        gl_lds16(gB0, lB0);
        gl_lds16(gB1, lB1);
        gA0 += 32; gA1 += 32; gB0 += 32; gB1 += 32;
        __syncthreads();

        bf16x8 af[4], bfr[4];
#pragma unroll
        for (int mi = 0; mi < 4; ++mi)
            af[mi] = *reinterpret_cast<const bf16x8*>(&As[(arow + mi * 16) * 32 + koff]);
#pragma unroll
        for (int ni = 0; ni < 4; ++ni)
            bfr[ni] = *reinterpret_cast<const bf16x8*>(&Bs[(brow + ni * 16) * 32 + koff]);

#pragma unroll
        for (int mi = 0; mi < 4; ++mi)
#pragma unroll
            for (int ni = 0; ni < 4; ++ni)
                acc[mi][ni] = __builtin_amdgcn_mfma_f32_16x16x32_bf16(
                    af[mi], bfr[ni], acc[mi][ni], 0, 0, 0);

        __syncthreads();
    }

    // epilogue: D lane mapping col = l16, row = quad*4 + r
    const float* biasp = bias + bn * 128 + wn * 64 + l16;
    float* Cp = C + (size_t)(bm * 128 + wm * 64 + quad * 4) * OUT_F + bn * 128 + wn * 64 + l16;
#pragma unroll
    for (int mi = 0; mi < 4; ++mi) {
#pragma unroll
        for (int ni = 0; ni < 4; ++ni) {
            float bv = biasp[ni * 16];
#pragma unroll
            for (int r = 0; r < 4; ++r)
                Cp[(size_t)(mi * 16 + r) * OUT_F + ni * 16] = acc[mi][ni][r] + bv;
        }
    }
}

extern "C" void kernel_launch(void* const* d_in, const int* in_sizes, int n_in,
                              void* d_out, int out_size, void* d_ws, size_t ws_size,
                              hipStream_t stream) {
    const float* x       = (const float*)d_in[0];
    const int*   packed  = (const int*)d_in[1];
    const float* scales  = (const float*)d_in[2];
    const float* offsets = (const float*)d_in[3];
    const float* bias    = (const float*)d_in[4];
    float* out = (float*)d_out;

    ushort* xb = (ushort*)d_ws;                                    // 64 MiB
    ushort* wb = (ushort*)((char*)d_ws + (size_t)M_TOT * IN_F * 2); // 32 MiB

    prep_kernel<<<X_BLOCKS + W_BLOCKS, 256, 0, stream>>>(x, xb, packed, scales, offsets, wb);

    dim3 grid(OUT_F / 128, M_TOT / 128);   // (32, 64)
    gemm_kernel<<<grid, 256, 0, stream>>>(xb, wb, bias, out);
}